// Round 11
// baseline (117.758 us; speedup 1.0000x reference)
//
#include <hip/hip_runtime.h>

#define D 128
#define PSHIFT 6
#define PSIZE 64             // dsts per partition
#define EDGES_PER_BLK 4096   // bin kernels: 512 thr x 8 edges
#define CAP 2048             // max records per partition (mean 1280, +21 sigma)
#define MAXPART 1024
#define NCHUNK 4             // dim chunks: 32 dims = 64B slice per node, 3.2MB/chunk

typedef __attribute__((ext_vector_type(8))) short bf16x8;
typedef __attribute__((ext_vector_type(4))) float f32x4;

__device__ __forceinline__ unsigned short f2bf(float f) {
  unsigned int u = __float_as_uint(f);
  u = (u + 0x7fffu + ((u >> 16) & 1)) >> 16;
  return (unsigned short)u;
}

// ---------------------------------------------------------------------------
// Fused Pass 0+A: blocks [0, cvtBlocks) convert h f32 -> h16 in CHUNK-MAJOR
// layout h16c[c][n][32] (c = dim>>5); remaining blocks LDS-histogram 4096
// edges into 1024 partition bins + one global atomic per nonzero bin.
// ---------------------------------------------------------------------------
__global__ __launch_bounds__(512) void cvt_hist_kernel(
    const float* __restrict__ h, unsigned short* __restrict__ h16, int total4,
    const int* __restrict__ edst, int* __restrict__ g_hist, int E,
    int cvtBlocks, int N) {
  if ((int)blockIdx.x < cvtBlocks) {
    int i = blockIdx.x * 512 + threadIdx.x;
    if (i >= total4) return;
    float4 v = ((const float4*)h)[i];
    ushort4 o;
    o.x = f2bf(v.x); o.y = f2bf(v.y); o.z = f2bf(v.z); o.w = f2bf(v.w);
    int f = i * 4;
    int n = f >> 7;
    int d = f & 127;
    int c = d >> 5;
    int wi = d & 31;
    ((ushort4*)h16)[(size_t)c * N * 8 + n * 8 + (wi >> 2)] = o;
    return;
  }
  __shared__ int cnt[MAXPART];
  int t = threadIdx.x;
  cnt[t] = 0; cnt[t + 512] = 0;
  __syncthreads();
  int eb = (blockIdx.x - cvtBlocks) * EDGES_PER_BLK;
#pragma unroll
  for (int q = 0; q < 8; ++q) {
    int e = eb + q * 512 + t;
    if (e < E) atomicAdd(&cnt[edst[e] >> PSHIFT], 1);
  }
  __syncthreads();
  int c = cnt[t];
  if (c > 0) atomicAdd(&g_hist[t], c);
  c = cnt[t + 512];
  if (c > 0) atomicAdd(&g_hist[t + 512], c);
}

// ---------------------------------------------------------------------------
// Pass B: single-block pair-scan of 1024 partition counts -> part_off
// (exclusive, +end sentinel) and g_cursor (running allocator).
// ---------------------------------------------------------------------------
__global__ __launch_bounds__(512) void part_scan_kernel(
    const int* __restrict__ g_hist, int* __restrict__ part_off,
    int* __restrict__ g_cursor, int E, int npart) {
  __shared__ int ts[512];
  int t = threadIdx.x;
  int i0 = 2 * t, i1 = 2 * t + 1;
  int v0 = (i0 < npart) ? g_hist[i0] : 0;
  int v1 = (i1 < npart) ? g_hist[i1] : 0;
  ts[t] = v0 + v1;
  __syncthreads();
  for (int off = 1; off < 512; off <<= 1) {
    int x = (t >= off) ? ts[t - off] : 0;
    __syncthreads();
    ts[t] += x;
    __syncthreads();
  }
  int excl = ts[t] - (v0 + v1);
  if (i0 < npart) { part_off[i0] = excl; g_cursor[i0] = excl; }
  if (i1 < npart) { part_off[i1] = excl + v0; g_cursor[i1] = excl + v0; }
  if (t == 0) part_off[npart] = E;
}

// ---------------------------------------------------------------------------
// Pass C: LDS-binned scatter (unchanged).  Record: {src | (dst&63)<<16, coeff}.
// ---------------------------------------------------------------------------
__global__ __launch_bounds__(512) void bin_scatter_kernel(
    const float* __restrict__ alpha, const float* __restrict__ ew,
    const int* __restrict__ node_id, const int* __restrict__ esrc,
    const int* __restrict__ edst, int* __restrict__ g_cursor,
    int2* __restrict__ recs, int E, int gene_num) {
  __shared__ int2 lrec[EDGES_PER_BLK];            // 32 KB
  __shared__ unsigned short lbin[EDGES_PER_BLK];  // 8 KB
  __shared__ int cnt[MAXPART], offl[MAXPART], gbase[MAXPART];  // 12 KB
  __shared__ int ts[512];

  int t = threadIdx.x;
  cnt[t] = 0; cnt[t + 512] = 0;
  __syncthreads();

  int eb = blockIdx.x * EDGES_PER_BLK;
  int rx[8]; float rc[8]; int rb[8]; int rk[8];
#pragma unroll
  for (int q = 0; q < 8; ++q) {
    int e = eb + q * 512 + t;
    rk[q] = -1;
    if (e < E) {
      int src = esrc[e];
      int dst = edst[e];
      int sid = node_id[src];
      int did = node_id[dst];
      int idx;
      if (sid >= 0) idx = (did >= 0) ? gene_num : sid;
      else          idx = (did >= 0) ? did : (gene_num + 1);
      rc[q] = alpha[idx] * ew[e];
      rx[q] = src | ((dst & (PSIZE - 1)) << 16);
      int b = dst >> PSHIFT;
      rb[q] = b;
      rk[q] = atomicAdd(&cnt[b], 1);
    }
  }
  __syncthreads();

  // pair-scan of 1024 bins -> offl exclusive
  int c0 = cnt[2 * t], c1 = cnt[2 * t + 1];
  ts[t] = c0 + c1;
  __syncthreads();
  for (int off = 1; off < 512; off <<= 1) {
    int x = (t >= off) ? ts[t - off] : 0;
    __syncthreads();
    ts[t] += x;
    __syncthreads();
  }
  int exclp = ts[t] - (c0 + c1);
  offl[2 * t] = exclp;
  offl[2 * t + 1] = exclp + c0;
  __syncthreads();

  // place into LDS (sorted by bin)
#pragma unroll
  for (int q = 0; q < 8; ++q) {
    if (rk[q] >= 0) {
      int ls = offl[rb[q]] + rk[q];
      lrec[ls] = make_int2(rx[q], __float_as_int(rc[q]));
      lbin[ls] = (unsigned short)rb[q];
    }
  }
  __syncthreads();

  // reserve global runs (one atomic per nonzero bin)
  {
    int c = cnt[t];
    if (c > 0) gbase[t] = atomicAdd(&g_cursor[t], c);
    c = cnt[t + 512];
    if (c > 0) gbase[t + 512] = atomicAdd(&g_cursor[t + 512], c);
  }
  __syncthreads();

  // coalesced run write-out
  int tot = E - eb;
  if (tot > EDGES_PER_BLK) tot = EDGES_PER_BLK;
  for (int s = t; s < tot; s += 512) {
    int b = lbin[s];
    recs[gbase[b] + (s - offl[b])] = lrec[s];
  }
}

// ---------------------------------------------------------------------------
// Pass D: per-(partition, dim-chunk) accumulate.  bid = p*4 + c; with
// round-robin block->XCD dispatch (bid%8), chunk c lands only on XCDs with
// xcd&3==c, so each XCD's h16 gathers touch ONE 3.2MB slice -> L2-resident.
// Block: stage partition's records to LDS counting-sorted by dst&63, then
// 8 waves x (8 dsts as 4 interleaved pairs).  Wave batch = 4 edges x 16
// lanes (2 dims/lane): uniform-ish lrec reads (16-way broadcast), 64B/src
// full-line L2 gathers, 16 record-slots (8 loads) in flight per pair.
// shfl_xor (16,32) reduce, 128B coalesced row-slice writes.
// ---------------------------------------------------------------------------
__global__ __launch_bounds__(512) void part_acc_kernel(
    const unsigned short* __restrict__ h16, const int2* __restrict__ recs,
    const int* __restrict__ part_off, float* __restrict__ neigh, int N) {
  __shared__ int2 lrec[CAP];              // 16 KB, sorted by dst-low
  __shared__ int cnt[PSIZE], offl[PSIZE];

  int t = threadIdx.x;
  int p = blockIdx.x >> 2;
  int chunk = blockIdx.x & 3;
  if (t < PSIZE) cnt[t] = 0;
  __syncthreads();

  int start = part_off[p];
  int R = part_off[p + 1] - start;
  if (R > CAP) R = CAP;   // statistically impossible overflow guard

  int2 rq[4]; int dlq[4]; int rkq[4];
#pragma unroll
  for (int q = 0; q < 4; ++q) {
    int s = q * 512 + t;
    rkq[q] = -1;
    if (s < R) {
      int2 r = recs[start + s];
      rq[q] = r;
      int dl = (r.x >> 16) & (PSIZE - 1);
      dlq[q] = dl;
      rkq[q] = atomicAdd(&cnt[dl], 1);
    }
  }
  __syncthreads();

  // scan 64 bins
  if (t < PSIZE) offl[t] = cnt[t];
  __syncthreads();
  for (int off = 1; off < PSIZE; off <<= 1) {
    int x = 0;
    if (t < PSIZE && t >= off) x = offl[t - off];
    __syncthreads();
    if (t < PSIZE) offl[t] += x;
    __syncthreads();
  }
  if (t < PSIZE) offl[t] -= cnt[t];
  __syncthreads();

#pragma unroll
  for (int q = 0; q < 4; ++q)
    if (rkq[q] >= 0) lrec[offl[dlq[q]] + rkq[q]] = rq[q];
  __syncthreads();

  int w = t >> 6;
  int l = t & 63;
  int esub = l >> 4;        // 0..3: edge slot within batch
  int dpair = l & 15;       // dim pair within chunk
  // chunk slice, viewed as uint (2 bf16): node row = 16 uints
  const unsigned int* hp = ((const unsigned int*)h16) + (size_t)chunk * N * 16 + dpair;

  for (int dd = 0; dd < 4; ++dd) {
    int dlA = w * 8 + 2 * dd;
    int dlB = dlA + 1;
    int cA = cnt[dlA], oA = offl[dlA];
    int cB = cnt[dlB], oB = offl[dlB];
    float axA = 0.f, ayA = 0.f, axB = 0.f, ayB = 0.f;
    int cmax = (cA > cB) ? cA : cB;
    for (int k = 0; k < cmax; k += 16) {
      float cfA[4], cfB[4];
      unsigned int vA[4], vB[4];
      int aA[4], aB[4];
#pragma unroll
      for (int q = 0; q < 4; ++q) {
        int sl = k + 4 * q + esub;
        int iA = oA + sl; iA = (iA < CAP) ? iA : (CAP - 1);
        int iB = oB + sl; iB = (iB < CAP) ? iB : (CAP - 1);
        int2 rA = lrec[iA];
        int2 rB = lrec[iB];
        bool okA = sl < cA;
        bool okB = sl < cB;
        aA[q] = okA ? (rA.x & 0xffff) : 0;
        aB[q] = okB ? (rB.x & 0xffff) : 0;
        cfA[q] = okA ? __int_as_float(rA.y) : 0.f;
        cfB[q] = okB ? __int_as_float(rB.y) : 0.f;
      }
#pragma unroll
      for (int q = 0; q < 4; ++q) {
        vA[q] = hp[(size_t)aA[q] * 16];
        vB[q] = hp[(size_t)aB[q] * 16];
      }
#pragma unroll
      for (int q = 0; q < 4; ++q) {
        axA += cfA[q] * __uint_as_float(vA[q] << 16);
        ayA += cfA[q] * __uint_as_float(vA[q] & 0xffff0000u);
        axB += cfB[q] * __uint_as_float(vB[q] << 16);
        ayB += cfB[q] * __uint_as_float(vB[q] & 0xffff0000u);
      }
    }
    // reduce across the 4 edge-slot groups (stride 16, 32)
    axA += __shfl_xor(axA, 16); ayA += __shfl_xor(ayA, 16);
    axB += __shfl_xor(axB, 16); ayB += __shfl_xor(ayB, 16);
    axA += __shfl_xor(axA, 32); ayA += __shfl_xor(ayA, 32);
    axB += __shfl_xor(axB, 32); ayB += __shfl_xor(ayB, 32);

    int dstA = p * PSIZE + dlA;
    int dstB = p * PSIZE + dlB;
    if (l < 16) {
      if (dstA < N) {
        float inv = 1.0f / (float)(cA > 0 ? cA : 1);
        ((float2*)neigh)[(size_t)dstA * 64 + chunk * 16 + dpair] =
            make_float2(axA * inv, ayA * inv);
      }
      if (dstB < N) {
        float inv = 1.0f / (float)(cB > 0 ? cB : 1);
        ((float2*)neigh)[(size_t)dstB * 64 + chunk * 16 + dpair] =
            make_float2(axB * inv, ayB * inv);
      }
    }
  }
}

// ---------------------------------------------------------------------------
// MLP (MFMA): io = relu(io @ W.T + b), in place on d_out.  (unchanged)
// ---------------------------------------------------------------------------
__global__ __launch_bounds__(256) void mlp_mfma_kernel(
    const float* __restrict__ W, const float* __restrict__ bias,
    float* __restrict__ io, int N) {
  __shared__ __align__(16) unsigned short Wl[128 * 128];  // 32 KB bf16

  int t = threadIdx.x;
#pragma unroll
  for (int i = 0; i < 8; ++i) {
    int chunk = t + 256 * i;
    int row = chunk >> 4;
    int cb = chunk & 15;
    const float* gp = W + (size_t)row * 128 + cb * 8;
    float4 a = *(const float4*)gp;
    float4 b = *(const float4*)(gp + 4);
    bf16x8 v;
    v[0] = (short)f2bf(a.x); v[1] = (short)f2bf(a.y);
    v[2] = (short)f2bf(a.z); v[3] = (short)f2bf(a.w);
    v[4] = (short)f2bf(b.x); v[5] = (short)f2bf(b.y);
    v[6] = (short)f2bf(b.z); v[7] = (short)f2bf(b.w);
    *(bf16x8*)((char*)Wl + row * 256 + ((cb ^ (row & 7)) << 4)) = v;
  }
  __syncthreads();

  int l = t & 63;
  int w = t >> 6;
  int kg = l >> 4;
  int m_base = blockIdx.x * 64 + w * 16;
  int arow = m_base + (l & 15);
  if (arow >= N) arow = N - 1;

  bf16x8 af[4];
  const float* ap = io + (size_t)arow * 128 + kg * 8;
#pragma unroll
  for (int kk = 0; kk < 4; ++kk) {
    float4 a = *(const float4*)(ap + kk * 32);
    float4 b = *(const float4*)(ap + kk * 32 + 4);
    bf16x8 v;
    v[0] = (short)f2bf(a.x); v[1] = (short)f2bf(a.y);
    v[2] = (short)f2bf(a.z); v[3] = (short)f2bf(a.w);
    v[4] = (short)f2bf(b.x); v[5] = (short)f2bf(b.y);
    v[6] = (short)f2bf(b.z); v[7] = (short)f2bf(b.w);
    af[kk] = v;
  }

#pragma unroll
  for (int c = 0; c < 8; ++c) {
    f32x4 acc = {0.f, 0.f, 0.f, 0.f};
    int row_w = c * 16 + (l & 15);
    int rs = row_w & 7;
#pragma unroll
    for (int kk = 0; kk < 4; ++kk) {
      int cb = kk * 4 + kg;
      bf16x8 bf = *(bf16x8*)((char*)Wl + row_w * 256 + ((cb ^ rs) << 4));
      acc = __builtin_amdgcn_mfma_f32_16x16x32_bf16(af[kk], bf, acc, 0, 0, 0);
    }
    int j = c * 16 + (l & 15);
    float bj = bias[j];
#pragma unroll
    for (int r = 0; r < 4; ++r) {
      int m = m_base + kg * 4 + r;
      if (m < N) io[(size_t)m * 128 + j] = fmaxf(acc[r] + bj, 0.0f);
    }
  }
}

extern "C" void kernel_launch(void* const* d_in, const int* in_sizes, int n_in,
                              void* d_out, int out_size, void* d_ws, size_t ws_size,
                              hipStream_t stream) {
  const float* h     = (const float*)d_in[0];
  const float* alpha = (const float*)d_in[1];
  const float* ew    = (const float*)d_in[2];
  const float* W     = (const float*)d_in[3];
  const float* bias  = (const float*)d_in[4];
  const int* node_id = (const int*)d_in[5];
  const int* esrc    = (const int*)d_in[6];
  const int* edst    = (const int*)d_in[7];
  float* out = (float*)d_out;

  int E = in_sizes[2];
  int N = in_sizes[5];
  int gene_num = in_sizes[1] - 2;
  int npart = (N + PSIZE - 1) / PSIZE;          // 782 (must be <= 1024)
  int eblocks = (E + EDGES_PER_BLK - 1) / EDGES_PER_BLK;  // 245
  int total4 = N * D / 4;
  int cvtBlocks = (total4 + 511) / 512;         // 3125

  // workspace layout
  int* g_hist   = (int*)d_ws;                   // 1024
  int* part_off = g_hist + MAXPART;             // npart+1 (<=1025)
  int* g_cursor = part_off + MAXPART + 1;       // 1024
  size_t h16_off = ((size_t)(3 * MAXPART + 1) * sizeof(int) + 15) & ~(size_t)15;
  unsigned short* h16 = (unsigned short*)((char*)d_ws + h16_off);  // N*D bf16, chunk-major
  size_t rec_off = (h16_off + (size_t)N * D * sizeof(unsigned short) + 15) & ~(size_t)15;
  int2* recs = (int2*)((char*)d_ws + rec_off);  // E * 8B
  size_t need = rec_off + (size_t)E * sizeof(int2);
  if (ws_size < need) return;

  hipMemsetAsync(g_hist, 0, MAXPART * sizeof(int), stream);

  cvt_hist_kernel<<<cvtBlocks + eblocks, 512, 0, stream>>>(
      h, h16, total4, edst, g_hist, E, cvtBlocks, N);
  part_scan_kernel<<<1, 512, 0, stream>>>(g_hist, part_off, g_cursor, E, npart);
  bin_scatter_kernel<<<eblocks, 512, 0, stream>>>(alpha, ew, node_id, esrc,
                                                  edst, g_cursor, recs, E,
                                                  gene_num);
  part_acc_kernel<<<npart * NCHUNK, 512, 0, stream>>>(h16, recs, part_off, out, N);
  {
    int blocks = (N + 63) / 64;
    mlp_mfma_kernel<<<blocks, 256, 0, stream>>>(W, bias, out, N);
  }
}

// Round 12
// 116.732 us; speedup vs baseline: 1.0088x; 1.0088x over previous
//
#include <hip/hip_runtime.h>

#define D 128
#define PSHIFT 6
#define PSIZE 64             // dsts per partition
#define EDGES_PER_BLK 4096   // bin kernels: 512 thr x 8 edges
#define CAP 2048             // max records per partition (mean 1280, +21 sigma)
#define CAPP 3072            // padded LDS slots: CAP + 64*15 = 3008 <= 3072
#define MAXPART 1024
#define NCHUNK 4             // dim chunks: 32 dims = 64B/node, 3.2MB/chunk < 4MB L2

typedef __attribute__((ext_vector_type(8))) short bf16x8;
typedef __attribute__((ext_vector_type(4))) float f32x4;

__device__ __forceinline__ unsigned short f2bf(float f) {
  unsigned int u = __float_as_uint(f);
  u = (u + 0x7fffu + ((u >> 16) & 1)) >> 16;
  return (unsigned short)u;
}

// ---------------------------------------------------------------------------
// Fused Pass 0+A: blocks [0, cvtBlocks) convert h f32 -> h16 in CHUNK-MAJOR
// layout h16c[c][n][32]; remaining blocks LDS-histogram edges into 1024
// partition bins + one global atomic per nonzero bin.
// ---------------------------------------------------------------------------
__global__ __launch_bounds__(512) void cvt_hist_kernel(
    const float* __restrict__ h, unsigned short* __restrict__ h16, int total4,
    const int* __restrict__ edst, int* __restrict__ g_hist, int E,
    int cvtBlocks, int N) {
  if ((int)blockIdx.x < cvtBlocks) {
    int i = blockIdx.x * 512 + threadIdx.x;
    if (i >= total4) return;
    float4 v = ((const float4*)h)[i];
    ushort4 o;
    o.x = f2bf(v.x); o.y = f2bf(v.y); o.z = f2bf(v.z); o.w = f2bf(v.w);
    int f = i * 4;
    int n = f >> 7;
    int d = f & 127;
    int c = d >> 5;
    int wi = d & 31;
    ((ushort4*)h16)[(size_t)c * N * 8 + n * 8 + (wi >> 2)] = o;
    return;
  }
  __shared__ int cnt[MAXPART];
  int t = threadIdx.x;
  cnt[t] = 0; cnt[t + 512] = 0;
  __syncthreads();
  int eb = (blockIdx.x - cvtBlocks) * EDGES_PER_BLK;
#pragma unroll
  for (int q = 0; q < 8; ++q) {
    int e = eb + q * 512 + t;
    if (e < E) atomicAdd(&cnt[edst[e] >> PSHIFT], 1);
  }
  __syncthreads();
  int c = cnt[t];
  if (c > 0) atomicAdd(&g_hist[t], c);
  c = cnt[t + 512];
  if (c > 0) atomicAdd(&g_hist[t + 512], c);
}

// ---------------------------------------------------------------------------
// Pass B: single-block pair-scan of 1024 partition counts -> part_off
// (exclusive, +end sentinel) and g_cursor (running allocator).
// ---------------------------------------------------------------------------
__global__ __launch_bounds__(512) void part_scan_kernel(
    const int* __restrict__ g_hist, int* __restrict__ part_off,
    int* __restrict__ g_cursor, int E, int npart) {
  __shared__ int ts[512];
  int t = threadIdx.x;
  int i0 = 2 * t, i1 = 2 * t + 1;
  int v0 = (i0 < npart) ? g_hist[i0] : 0;
  int v1 = (i1 < npart) ? g_hist[i1] : 0;
  ts[t] = v0 + v1;
  __syncthreads();
  for (int off = 1; off < 512; off <<= 1) {
    int x = (t >= off) ? ts[t - off] : 0;
    __syncthreads();
    ts[t] += x;
    __syncthreads();
  }
  int excl = ts[t] - (v0 + v1);
  if (i0 < npart) { part_off[i0] = excl; g_cursor[i0] = excl; }
  if (i1 < npart) { part_off[i1] = excl + v0; g_cursor[i1] = excl + v0; }
  if (t == 0) part_off[npart] = E;
}

// ---------------------------------------------------------------------------
// Pass C: LDS-binned scatter (unchanged).  Record: {src | (dst&63)<<16, coeff}.
// ---------------------------------------------------------------------------
__global__ __launch_bounds__(512) void bin_scatter_kernel(
    const float* __restrict__ alpha, const float* __restrict__ ew,
    const int* __restrict__ node_id, const int* __restrict__ esrc,
    const int* __restrict__ edst, int* __restrict__ g_cursor,
    int2* __restrict__ recs, int E, int gene_num) {
  __shared__ int2 lrec[EDGES_PER_BLK];            // 32 KB
  __shared__ unsigned short lbin[EDGES_PER_BLK];  // 8 KB
  __shared__ int cnt[MAXPART], offl[MAXPART], gbase[MAXPART];  // 12 KB
  __shared__ int ts[512];

  int t = threadIdx.x;
  cnt[t] = 0; cnt[t + 512] = 0;
  __syncthreads();

  int eb = blockIdx.x * EDGES_PER_BLK;
  int rx[8]; float rc[8]; int rb[8]; int rk[8];
#pragma unroll
  for (int q = 0; q < 8; ++q) {
    int e = eb + q * 512 + t;
    rk[q] = -1;
    if (e < E) {
      int src = esrc[e];
      int dst = edst[e];
      int sid = node_id[src];
      int did = node_id[dst];
      int idx;
      if (sid >= 0) idx = (did >= 0) ? gene_num : sid;
      else          idx = (did >= 0) ? did : (gene_num + 1);
      rc[q] = alpha[idx] * ew[e];
      rx[q] = src | ((dst & (PSIZE - 1)) << 16);
      int b = dst >> PSHIFT;
      rb[q] = b;
      rk[q] = atomicAdd(&cnt[b], 1);
    }
  }
  __syncthreads();

  // pair-scan of 1024 bins -> offl exclusive
  int c0 = cnt[2 * t], c1 = cnt[2 * t + 1];
  ts[t] = c0 + c1;
  __syncthreads();
  for (int off = 1; off < 512; off <<= 1) {
    int x = (t >= off) ? ts[t - off] : 0;
    __syncthreads();
    ts[t] += x;
    __syncthreads();
  }
  int exclp = ts[t] - (c0 + c1);
  offl[2 * t] = exclp;
  offl[2 * t + 1] = exclp + c0;
  __syncthreads();

  // place into LDS (sorted by bin)
#pragma unroll
  for (int q = 0; q < 8; ++q) {
    if (rk[q] >= 0) {
      int ls = offl[rb[q]] + rk[q];
      lrec[ls] = make_int2(rx[q], __float_as_int(rc[q]));
      lbin[ls] = (unsigned short)rb[q];
    }
  }
  __syncthreads();

  // reserve global runs (one atomic per nonzero bin)
  {
    int c = cnt[t];
    if (c > 0) gbase[t] = atomicAdd(&g_cursor[t], c);
    c = cnt[t + 512];
    if (c > 0) gbase[t + 512] = atomicAdd(&g_cursor[t + 512], c);
  }
  __syncthreads();

  // coalesced run write-out
  int tot = E - eb;
  if (tot > EDGES_PER_BLK) tot = EDGES_PER_BLK;
  for (int s = t; s < tot; s += 512) {
    int b = lbin[s];
    recs[gbase[b] + (s - offl[b])] = lrec[s];
  }
}

// ---------------------------------------------------------------------------
// Pass C2: per-partition sort-once.  Stage the partition's records, LDS
// counting-sort by dst&63, write back SORTED (coalesced, same range), and
// emit cnt_g/off_g[p*64+dl] so chunk blocks skip sorting entirely.
// ---------------------------------------------------------------------------
__global__ __launch_bounds__(512) void sort_kernel(
    int2* __restrict__ recs, const int* __restrict__ part_off,
    int* __restrict__ cnt_g, int* __restrict__ off_g) {
  __shared__ int2 lrec[CAP];              // 16 KB
  __shared__ int cnt[PSIZE], offl[PSIZE];

  int t = threadIdx.x;
  int p = blockIdx.x;
  if (t < PSIZE) cnt[t] = 0;
  __syncthreads();

  int start = part_off[p];
  int R = part_off[p + 1] - start;
  if (R > CAP) R = CAP;

  int2 rq[4]; int dlq[4]; int rkq[4];
#pragma unroll
  for (int q = 0; q < 4; ++q) {
    int s = q * 512 + t;
    rkq[q] = -1;
    if (s < R) {
      int2 r = recs[start + s];
      rq[q] = r;
      int dl = (r.x >> 16) & (PSIZE - 1);
      dlq[q] = dl;
      rkq[q] = atomicAdd(&cnt[dl], 1);
    }
  }
  __syncthreads();

  // exclusive scan of 64 bins
  if (t < PSIZE) offl[t] = cnt[t];
  __syncthreads();
  for (int off = 1; off < PSIZE; off <<= 1) {
    int x = 0;
    if (t < PSIZE && t >= off) x = offl[t - off];
    __syncthreads();
    if (t < PSIZE) offl[t] += x;
    __syncthreads();
  }
  if (t < PSIZE) offl[t] -= cnt[t];
  __syncthreads();

#pragma unroll
  for (int q = 0; q < 4; ++q)
    if (rkq[q] >= 0) lrec[offl[dlq[q]] + rkq[q]] = rq[q];
  __syncthreads();

  for (int s = t; s < R; s += 512) recs[start + s] = lrec[s];
  if (t < PSIZE) {
    cnt_g[p * PSIZE + t] = cnt[t];
    off_g[p * PSIZE + t] = offl[t];
  }
}

// ---------------------------------------------------------------------------
// Pass D: per-(partition, dim-chunk) accumulate.  bid = p*4 + c; round-robin
// block->XCD keeps chunk c on XCDs with xcd&3==c -> 3.2MB slice L2-resident.
// No sorting here: straight coalesced copy of pre-sorted records into LDS at
// per-bin PADDED offsets (pad to 16, zero-filled -> pad slots contribute 0,
// gather row 0).  Walk: 8 waves x 4 dst-pairs, 16-slot batches, uniform
// 16-lane LDS broadcasts, no per-slot selects; A/B tail via wave-uniform
// branches.  shfl_xor(16,32) reduce, 128B coalesced writes.
// ---------------------------------------------------------------------------
__global__ __launch_bounds__(512) void part_acc_kernel(
    const unsigned short* __restrict__ h16, const int2* __restrict__ recs,
    const int* __restrict__ part_off, const int* __restrict__ cnt_g,
    const int* __restrict__ off_g, float* __restrict__ neigh, int N) {
  __shared__ int2 lrec[CAPP];             // 24 KB, padded sorted records
  __shared__ int cnt[PSIZE], offl[PSIZE], padoff[PSIZE];

  int t = threadIdx.x;
  int p = blockIdx.x >> 2;
  int chunk = blockIdx.x & 3;

  int start = part_off[p];
  int R = part_off[p + 1] - start;
  if (R > CAP) R = CAP;

  if (t < PSIZE) {
    cnt[t] = cnt_g[p * PSIZE + t];
    offl[t] = off_g[p * PSIZE + t];
    padoff[t] = (cnt[t] + 15) & ~15;   // temp: padded size
  }
  // zero-fill padded buffer
  {
    int2 z = make_int2(0, 0);
#pragma unroll
    for (int q = 0; q < CAPP / 512; ++q) lrec[q * 512 + t] = z;
  }
  __syncthreads();
  // exclusive scan of padded sizes (64 wide)
  for (int off = 1; off < PSIZE; off <<= 1) {
    int x = 0;
    if (t < PSIZE && t >= off) x = padoff[t - off];
    __syncthreads();
    if (t < PSIZE) padoff[t] += x;
    __syncthreads();
  }
  if (t < PSIZE) padoff[t] -= (cnt[t] + 15) & ~15;
  __syncthreads();

  // coalesced copy into padded slots (records pre-sorted by dl)
  for (int s = t; s < R; s += 512) {
    int2 r = recs[start + s];
    int dl = (r.x >> 16) & (PSIZE - 1);
    lrec[padoff[dl] + (s - offl[dl])] = r;
  }
  __syncthreads();

  int w = t >> 6;
  int l = t & 63;
  int esub = l >> 4;        // 0..3: slot-quad lane group
  int dpair = l & 15;       // dim pair within chunk
  const unsigned int* hp =
      ((const unsigned int*)h16) + (size_t)chunk * N * 16 + dpair;

  for (int dd = 0; dd < 4; ++dd) {
    int dlA = w * 8 + 2 * dd;
    int dlB = dlA + 1;
    int cA = cnt[dlA], cB = cnt[dlB];
    int oA = padoff[dlA], oB = padoff[dlB];
    int cpA = (cA + 15) & ~15, cpB = (cB + 15) & ~15;
    float axA = 0.f, ayA = 0.f, axB = 0.f, ayB = 0.f;
    int cpm = (cpA > cpB) ? cpA : cpB;
    for (int k = 0; k < cpm; k += 16) {
      bool doA = k < cpA;   // wave-uniform
      bool doB = k < cpB;
      unsigned int aA[4], aB[4], vA[4], vB[4];
      float cfA[4], cfB[4];
      if (doA) {
#pragma unroll
        for (int q = 0; q < 4; ++q) {
          int2 r = lrec[oA + k + 4 * q + esub];
          aA[q] = r.x & 0xffff;
          cfA[q] = __int_as_float(r.y);
        }
#pragma unroll
        for (int q = 0; q < 4; ++q) vA[q] = hp[(size_t)aA[q] * 16];
      }
      if (doB) {
#pragma unroll
        for (int q = 0; q < 4; ++q) {
          int2 r = lrec[oB + k + 4 * q + esub];
          aB[q] = r.x & 0xffff;
          cfB[q] = __int_as_float(r.y);
        }
#pragma unroll
        for (int q = 0; q < 4; ++q) vB[q] = hp[(size_t)aB[q] * 16];
      }
      if (doA) {
#pragma unroll
        for (int q = 0; q < 4; ++q) {
          axA += cfA[q] * __uint_as_float(vA[q] << 16);
          ayA += cfA[q] * __uint_as_float(vA[q] & 0xffff0000u);
        }
      }
      if (doB) {
#pragma unroll
        for (int q = 0; q < 4; ++q) {
          axB += cfB[q] * __uint_as_float(vB[q] << 16);
          ayB += cfB[q] * __uint_as_float(vB[q] & 0xffff0000u);
        }
      }
    }
    // reduce across the 4 slot groups
    axA += __shfl_xor(axA, 16); ayA += __shfl_xor(ayA, 16);
    axB += __shfl_xor(axB, 16); ayB += __shfl_xor(ayB, 16);
    axA += __shfl_xor(axA, 32); ayA += __shfl_xor(ayA, 32);
    axB += __shfl_xor(axB, 32); ayB += __shfl_xor(ayB, 32);

    int dstA = p * PSIZE + dlA;
    int dstB = p * PSIZE + dlB;
    if (l < 16) {
      if (dstA < N) {
        float inv = 1.0f / (float)(cA > 0 ? cA : 1);
        ((float2*)neigh)[(size_t)dstA * 64 + chunk * 16 + dpair] =
            make_float2(axA * inv, ayA * inv);
      }
      if (dstB < N) {
        float inv = 1.0f / (float)(cB > 0 ? cB : 1);
        ((float2*)neigh)[(size_t)dstB * 64 + chunk * 16 + dpair] =
            make_float2(axB * inv, ayB * inv);
      }
    }
  }
}

// ---------------------------------------------------------------------------
// MLP (MFMA): io = relu(io @ W.T + b), in place on d_out.  (unchanged)
// ---------------------------------------------------------------------------
__global__ __launch_bounds__(256) void mlp_mfma_kernel(
    const float* __restrict__ W, const float* __restrict__ bias,
    float* __restrict__ io, int N) {
  __shared__ __align__(16) unsigned short Wl[128 * 128];  // 32 KB bf16

  int t = threadIdx.x;
#pragma unroll
  for (int i = 0; i < 8; ++i) {
    int chunk = t + 256 * i;
    int row = chunk >> 4;
    int cb = chunk & 15;
    const float* gp = W + (size_t)row * 128 + cb * 8;
    float4 a = *(const float4*)gp;
    float4 b = *(const float4*)(gp + 4);
    bf16x8 v;
    v[0] = (short)f2bf(a.x); v[1] = (short)f2bf(a.y);
    v[2] = (short)f2bf(a.z); v[3] = (short)f2bf(a.w);
    v[4] = (short)f2bf(b.x); v[5] = (short)f2bf(b.y);
    v[6] = (short)f2bf(b.z); v[7] = (short)f2bf(b.w);
    *(bf16x8*)((char*)Wl + row * 256 + ((cb ^ (row & 7)) << 4)) = v;
  }
  __syncthreads();

  int l = t & 63;
  int w = t >> 6;
  int kg = l >> 4;
  int m_base = blockIdx.x * 64 + w * 16;
  int arow = m_base + (l & 15);
  if (arow >= N) arow = N - 1;

  bf16x8 af[4];
  const float* ap = io + (size_t)arow * 128 + kg * 8;
#pragma unroll
  for (int kk = 0; kk < 4; ++kk) {
    float4 a = *(const float4*)(ap + kk * 32);
    float4 b = *(const float4*)(ap + kk * 32 + 4);
    bf16x8 v;
    v[0] = (short)f2bf(a.x); v[1] = (short)f2bf(a.y);
    v[2] = (short)f2bf(a.z); v[3] = (short)f2bf(a.w);
    v[4] = (short)f2bf(b.x); v[5] = (short)f2bf(b.y);
    v[6] = (short)f2bf(b.z); v[7] = (short)f2bf(b.w);
    af[kk] = v;
  }

#pragma unroll
  for (int c = 0; c < 8; ++c) {
    f32x4 acc = {0.f, 0.f, 0.f, 0.f};
    int row_w = c * 16 + (l & 15);
    int rs = row_w & 7;
#pragma unroll
    for (int kk = 0; kk < 4; ++kk) {
      int cb = kk * 4 + kg;
      bf16x8 bf = *(bf16x8*)((char*)Wl + row_w * 256 + ((cb ^ rs) << 4));
      acc = __builtin_amdgcn_mfma_f32_16x16x32_bf16(af[kk], bf, acc, 0, 0, 0);
    }
    int j = c * 16 + (l & 15);
    float bj = bias[j];
#pragma unroll
    for (int r = 0; r < 4; ++r) {
      int m = m_base + kg * 4 + r;
      if (m < N) io[(size_t)m * 128 + j] = fmaxf(acc[r] + bj, 0.0f);
    }
  }
}

extern "C" void kernel_launch(void* const* d_in, const int* in_sizes, int n_in,
                              void* d_out, int out_size, void* d_ws, size_t ws_size,
                              hipStream_t stream) {
  const float* h     = (const float*)d_in[0];
  const float* alpha = (const float*)d_in[1];
  const float* ew    = (const float*)d_in[2];
  const float* W     = (const float*)d_in[3];
  const float* bias  = (const float*)d_in[4];
  const int* node_id = (const int*)d_in[5];
  const int* esrc    = (const int*)d_in[6];
  const int* edst    = (const int*)d_in[7];
  float* out = (float*)d_out;

  int E = in_sizes[2];
  int N = in_sizes[5];
  int gene_num = in_sizes[1] - 2;
  int npart = (N + PSIZE - 1) / PSIZE;          // 782 (must be <= 1024)
  int eblocks = (E + EDGES_PER_BLK - 1) / EDGES_PER_BLK;  // 245
  int total4 = N * D / 4;
  int cvtBlocks = (total4 + 511) / 512;         // 3125

  // workspace layout
  int* g_hist   = (int*)d_ws;                   // 1024
  int* part_off = g_hist + MAXPART;             // npart+1 (<=1025)
  int* g_cursor = part_off + MAXPART + 1;       // 1024
  int* cnt_g    = g_cursor + MAXPART;           // npart*64 <= 65536
  int* off_g    = cnt_g + MAXPART * PSIZE;      // npart*64 <= 65536
  size_t h16_off = ((size_t)(3 * MAXPART + 1 + 2 * MAXPART * PSIZE) * sizeof(int)
                    + 15) & ~(size_t)15;
  unsigned short* h16 = (unsigned short*)((char*)d_ws + h16_off);  // chunk-major
  size_t rec_off = (h16_off + (size_t)N * D * sizeof(unsigned short) + 15) & ~(size_t)15;
  int2* recs = (int2*)((char*)d_ws + rec_off);  // E * 8B
  size_t need = rec_off + (size_t)E * sizeof(int2);
  if (ws_size < need) return;

  hipMemsetAsync(g_hist, 0, MAXPART * sizeof(int), stream);

  cvt_hist_kernel<<<cvtBlocks + eblocks, 512, 0, stream>>>(
      h, h16, total4, edst, g_hist, E, cvtBlocks, N);
  part_scan_kernel<<<1, 512, 0, stream>>>(g_hist, part_off, g_cursor, E, npart);
  bin_scatter_kernel<<<eblocks, 512, 0, stream>>>(alpha, ew, node_id, esrc,
                                                  edst, g_cursor, recs, E,
                                                  gene_num);
  sort_kernel<<<npart, 512, 0, stream>>>(recs, part_off, cnt_g, off_g);
  part_acc_kernel<<<npart * NCHUNK, 512, 0, stream>>>(h16, recs, part_off,
                                                      cnt_g, off_g, out, N);
  {
    int blocks = (N + 63) / 64;
    mlp_mfma_kernel<<<blocks, 256, 0, stream>>>(W, bias, out, N);
  }
}

// Round 13
// 108.317 us; speedup vs baseline: 1.0872x; 1.0777x over previous
//
#include <hip/hip_runtime.h>

#define D 128
#define PSHIFT 6
#define PSIZE 64             // dsts per partition
#define EDGES_PER_BLK 4096   // bin kernels: 512 thr x 8 edges
#define CAP 2048             // max records per partition (mean 1280, +21 sigma)
#define CAPP 2244            // padded LDS slots: CAP + 64*3 + align slack
#define MAXPART 1024
#define NCHUNK 4             // dim chunks: 32 dims = 64B/node, 3.2MB/chunk < 4MB L2

typedef __attribute__((ext_vector_type(8))) short bf16x8;
typedef __attribute__((ext_vector_type(4))) float f32x4;

__device__ __forceinline__ unsigned short f2bf(float f) {
  unsigned int u = __float_as_uint(f);
  u = (u + 0x7fffu + ((u >> 16) & 1)) >> 16;
  return (unsigned short)u;
}

// ---------------------------------------------------------------------------
// Fused Pass 0+A: blocks [0, cvtBlocks) convert h f32 -> h16 in CHUNK-MAJOR
// layout h16c[c][n][32]; remaining blocks LDS-histogram edges into 1024
// partition bins + one global atomic per nonzero bin.
// ---------------------------------------------------------------------------
__global__ __launch_bounds__(512) void cvt_hist_kernel(
    const float* __restrict__ h, unsigned short* __restrict__ h16, int total4,
    const int* __restrict__ edst, int* __restrict__ g_hist, int E,
    int cvtBlocks, int N) {
  if ((int)blockIdx.x < cvtBlocks) {
    int i = blockIdx.x * 512 + threadIdx.x;
    if (i >= total4) return;
    float4 v = ((const float4*)h)[i];
    ushort4 o;
    o.x = f2bf(v.x); o.y = f2bf(v.y); o.z = f2bf(v.z); o.w = f2bf(v.w);
    int f = i * 4;
    int n = f >> 7;
    int d = f & 127;
    int c = d >> 5;
    int wi = d & 31;
    ((ushort4*)h16)[(size_t)c * N * 8 + n * 8 + (wi >> 2)] = o;
    return;
  }
  __shared__ int cnt[MAXPART];
  int t = threadIdx.x;
  cnt[t] = 0; cnt[t + 512] = 0;
  __syncthreads();
  int eb = (blockIdx.x - cvtBlocks) * EDGES_PER_BLK;
#pragma unroll
  for (int q = 0; q < 8; ++q) {
    int e = eb + q * 512 + t;
    if (e < E) atomicAdd(&cnt[edst[e] >> PSHIFT], 1);
  }
  __syncthreads();
  int c = cnt[t];
  if (c > 0) atomicAdd(&g_hist[t], c);
  c = cnt[t + 512];
  if (c > 0) atomicAdd(&g_hist[t + 512], c);
}

// ---------------------------------------------------------------------------
// Pass B: single-block pair-scan of 1024 partition counts -> part_off
// (exclusive, +end sentinel) and g_cursor (running allocator).
// ---------------------------------------------------------------------------
__global__ __launch_bounds__(512) void part_scan_kernel(
    const int* __restrict__ g_hist, int* __restrict__ part_off,
    int* __restrict__ g_cursor, int E, int npart) {
  __shared__ int ts[512];
  int t = threadIdx.x;
  int i0 = 2 * t, i1 = 2 * t + 1;
  int v0 = (i0 < npart) ? g_hist[i0] : 0;
  int v1 = (i1 < npart) ? g_hist[i1] : 0;
  ts[t] = v0 + v1;
  __syncthreads();
  for (int off = 1; off < 512; off <<= 1) {
    int x = (t >= off) ? ts[t - off] : 0;
    __syncthreads();
    ts[t] += x;
    __syncthreads();
  }
  int excl = ts[t] - (v0 + v1);
  if (i0 < npart) { part_off[i0] = excl; g_cursor[i0] = excl; }
  if (i1 < npart) { part_off[i1] = excl + v0; g_cursor[i1] = excl + v0; }
  if (t == 0) part_off[npart] = E;
}

// ---------------------------------------------------------------------------
// Pass C: LDS-binned scatter (unchanged).  Record: {src | (dst&63)<<16, coeff}.
// ---------------------------------------------------------------------------
__global__ __launch_bounds__(512) void bin_scatter_kernel(
    const float* __restrict__ alpha, const float* __restrict__ ew,
    const int* __restrict__ node_id, const int* __restrict__ esrc,
    const int* __restrict__ edst, int* __restrict__ g_cursor,
    int2* __restrict__ recs, int E, int gene_num) {
  __shared__ int2 lrec[EDGES_PER_BLK];            // 32 KB
  __shared__ unsigned short lbin[EDGES_PER_BLK];  // 8 KB
  __shared__ int cnt[MAXPART], offl[MAXPART], gbase[MAXPART];  // 12 KB
  __shared__ int ts[512];

  int t = threadIdx.x;
  cnt[t] = 0; cnt[t + 512] = 0;
  __syncthreads();

  int eb = blockIdx.x * EDGES_PER_BLK;
  int rx[8]; float rc[8]; int rb[8]; int rk[8];
#pragma unroll
  for (int q = 0; q < 8; ++q) {
    int e = eb + q * 512 + t;
    rk[q] = -1;
    if (e < E) {
      int src = esrc[e];
      int dst = edst[e];
      int sid = node_id[src];
      int did = node_id[dst];
      int idx;
      if (sid >= 0) idx = (did >= 0) ? gene_num : sid;
      else          idx = (did >= 0) ? did : (gene_num + 1);
      rc[q] = alpha[idx] * ew[e];
      rx[q] = src | ((dst & (PSIZE - 1)) << 16);
      int b = dst >> PSHIFT;
      rb[q] = b;
      rk[q] = atomicAdd(&cnt[b], 1);
    }
  }
  __syncthreads();

  // pair-scan of 1024 bins -> offl exclusive
  int c0 = cnt[2 * t], c1 = cnt[2 * t + 1];
  ts[t] = c0 + c1;
  __syncthreads();
  for (int off = 1; off < 512; off <<= 1) {
    int x = (t >= off) ? ts[t - off] : 0;
    __syncthreads();
    ts[t] += x;
    __syncthreads();
  }
  int exclp = ts[t] - (c0 + c1);
  offl[2 * t] = exclp;
  offl[2 * t + 1] = exclp + c0;
  __syncthreads();

  // place into LDS (sorted by bin)
#pragma unroll
  for (int q = 0; q < 8; ++q) {
    if (rk[q] >= 0) {
      int ls = offl[rb[q]] + rk[q];
      lrec[ls] = make_int2(rx[q], __float_as_int(rc[q]));
      lbin[ls] = (unsigned short)rb[q];
    }
  }
  __syncthreads();

  // reserve global runs (one atomic per nonzero bin)
  {
    int c = cnt[t];
    if (c > 0) gbase[t] = atomicAdd(&g_cursor[t], c);
    c = cnt[t + 512];
    if (c > 0) gbase[t + 512] = atomicAdd(&g_cursor[t + 512], c);
  }
  __syncthreads();

  // coalesced run write-out
  int tot = E - eb;
  if (tot > EDGES_PER_BLK) tot = EDGES_PER_BLK;
  for (int s = t; s < tot; s += 512) {
    int b = lbin[s];
    recs[gbase[b] + (s - offl[b])] = lrec[s];
  }
}

// ---------------------------------------------------------------------------
// Pass C2: per-partition sort-once.  Stage the partition's records, LDS
// counting-sort by dst&63, write back SORTED (coalesced), and emit
// cnt_g / off_g (exact excl) / pad_g (pad-to-4 excl) per (p, dl).
// ---------------------------------------------------------------------------
__global__ __launch_bounds__(512) void sort_kernel(
    int2* __restrict__ recs, const int* __restrict__ part_off,
    int* __restrict__ cnt_g, int* __restrict__ off_g,
    int* __restrict__ pad_g) {
  __shared__ int2 lrec[CAP];              // 16 KB
  __shared__ int cnt[PSIZE], offl[PSIZE], padl[PSIZE];

  int t = threadIdx.x;
  int p = blockIdx.x;
  if (t < PSIZE) cnt[t] = 0;
  __syncthreads();

  int start = part_off[p];
  int R = part_off[p + 1] - start;
  if (R > CAP) R = CAP;

  int2 rq[4]; int dlq[4]; int rkq[4];
#pragma unroll
  for (int q = 0; q < 4; ++q) {
    int s = q * 512 + t;
    rkq[q] = -1;
    if (s < R) {
      int2 r = recs[start + s];
      rq[q] = r;
      int dl = (r.x >> 16) & (PSIZE - 1);
      dlq[q] = dl;
      rkq[q] = atomicAdd(&cnt[dl], 1);
    }
  }
  __syncthreads();

  // exclusive scans of 64 bins: exact (offl) and padded-to-4 (padl)
  if (t < PSIZE) { offl[t] = cnt[t]; padl[t] = (cnt[t] + 3) & ~3; }
  __syncthreads();
  for (int off = 1; off < PSIZE; off <<= 1) {
    int x = 0, y = 0;
    if (t < PSIZE && t >= off) { x = offl[t - off]; y = padl[t - off]; }
    __syncthreads();
    if (t < PSIZE) { offl[t] += x; padl[t] += y; }
    __syncthreads();
  }
  if (t < PSIZE) {
    offl[t] -= cnt[t];
    padl[t] -= (cnt[t] + 3) & ~3;
  }
  __syncthreads();

#pragma unroll
  for (int q = 0; q < 4; ++q)
    if (rkq[q] >= 0) lrec[offl[dlq[q]] + rkq[q]] = rq[q];
  __syncthreads();

  for (int s = t; s < R; s += 512) recs[start + s] = lrec[s];
  if (t < PSIZE) {
    cnt_g[p * PSIZE + t] = cnt[t];
    off_g[p * PSIZE + t] = offl[t];
    pad_g[p * PSIZE + t] = padl[t];
  }
}

// ---------------------------------------------------------------------------
// Pass D: per-(partition, dim-chunk) accumulate.  bid = p*4 + c; round-robin
// block->XCD keeps chunk c on XCDs with xcd&3==c -> 3.2MB slice L2-resident.
// Staging: zero-fill padded LDS, placement-copy pre-sorted records at
// pad-to-4 offsets.  Walk: 8 waves; each wave = 4 INDEPENDENT dsts (16-lane
// group per dst, lane = dim pair), 2 quads of dsts per wave.  Per group:
// 4-deep record batches (uniform LDS broadcast), divergent per-group loop
// bound (pad slots are zero: coeff 0, row 0).  No cross-lane reduce; each
// group writes its dst's 32-dim slice (128B coalesced).
// ---------------------------------------------------------------------------
__global__ __launch_bounds__(512) void part_acc_kernel(
    const unsigned short* __restrict__ h16, const int2* __restrict__ recs,
    const int* __restrict__ part_off, const int* __restrict__ cnt_g,
    const int* __restrict__ off_g, const int* __restrict__ pad_g,
    float* __restrict__ neigh, int N) {
  __shared__ int2 lrec[CAPP];             // ~17.6 KB, padded sorted records
  __shared__ int cnt[PSIZE], offl[PSIZE], padl[PSIZE];

  int t = threadIdx.x;
  int p = blockIdx.x >> 2;
  int chunk = blockIdx.x & 3;

  int start = part_off[p];
  int R = part_off[p + 1] - start;
  if (R > CAP) R = CAP;

  if (t < PSIZE) {
    cnt[t] = cnt_g[p * PSIZE + t];
    offl[t] = off_g[p * PSIZE + t];
    padl[t] = pad_g[p * PSIZE + t];
  }
  // zero-fill padded buffer
  {
    int2 z = make_int2(0, 0);
    for (int q = t; q < CAPP; q += 512) lrec[q] = z;
  }
  __syncthreads();

  // placement copy into padded slots (records pre-sorted by dl)
  for (int s = t; s < R; s += 512) {
    int2 r = recs[start + s];
    int dl = (r.x >> 16) & (PSIZE - 1);
    lrec[padl[dl] + (s - offl[dl])] = r;
  }
  __syncthreads();

  int w = t >> 6;
  int l = t & 63;
  int esub = l >> 4;        // 0..3: which dst in the quad
  int dpair = l & 15;       // dim pair within chunk (16 uints = 32 dims)
  const unsigned int* hpc =
      ((const unsigned int*)h16) + (size_t)chunk * N * 16 + dpair;

#pragma unroll
  for (int h2 = 0; h2 < 2; ++h2) {
    int myDl = w * 8 + h2 * 4 + esub;
    int myCnt = cnt[myDl];
    int myOff = padl[myDl];
    int myPad = (myCnt + 3) & ~3;
    float ax = 0.f, ay = 0.f;
    for (int k = 0; k < myPad; k += 4) {   // per-group divergent bound
      int2 r0 = lrec[myOff + k + 0];
      int2 r1 = lrec[myOff + k + 1];
      int2 r2 = lrec[myOff + k + 2];
      int2 r3 = lrec[myOff + k + 3];
      unsigned int v0 = hpc[(size_t)(r0.x & 0xffff) * 16];
      unsigned int v1 = hpc[(size_t)(r1.x & 0xffff) * 16];
      unsigned int v2 = hpc[(size_t)(r2.x & 0xffff) * 16];
      unsigned int v3 = hpc[(size_t)(r3.x & 0xffff) * 16];
      float c0 = __int_as_float(r0.y), c1 = __int_as_float(r1.y);
      float c2 = __int_as_float(r2.y), c3 = __int_as_float(r3.y);
      ax += c0 * __uint_as_float(v0 << 16);
      ay += c0 * __uint_as_float(v0 & 0xffff0000u);
      ax += c1 * __uint_as_float(v1 << 16);
      ay += c1 * __uint_as_float(v1 & 0xffff0000u);
      ax += c2 * __uint_as_float(v2 << 16);
      ay += c2 * __uint_as_float(v2 & 0xffff0000u);
      ax += c3 * __uint_as_float(v3 << 16);
      ay += c3 * __uint_as_float(v3 & 0xffff0000u);
    }
    int dst = p * PSIZE + myDl;
    if (dst < N) {
      float inv = 1.0f / (float)(myCnt > 0 ? myCnt : 1);
      ((float2*)neigh)[(size_t)dst * 64 + chunk * 16 + dpair] =
          make_float2(ax * inv, ay * inv);
    }
  }
}

// ---------------------------------------------------------------------------
// MLP (MFMA): io = relu(io @ W.T + b), in place on d_out.  (unchanged)
// ---------------------------------------------------------------------------
__global__ __launch_bounds__(256) void mlp_mfma_kernel(
    const float* __restrict__ W, const float* __restrict__ bias,
    float* __restrict__ io, int N) {
  __shared__ __align__(16) unsigned short Wl[128 * 128];  // 32 KB bf16

  int t = threadIdx.x;
#pragma unroll
  for (int i = 0; i < 8; ++i) {
    int chunk = t + 256 * i;
    int row = chunk >> 4;
    int cb = chunk & 15;
    const float* gp = W + (size_t)row * 128 + cb * 8;
    float4 a = *(const float4*)gp;
    float4 b = *(const float4*)(gp + 4);
    bf16x8 v;
    v[0] = (short)f2bf(a.x); v[1] = (short)f2bf(a.y);
    v[2] = (short)f2bf(a.z); v[3] = (short)f2bf(a.w);
    v[4] = (short)f2bf(b.x); v[5] = (short)f2bf(b.y);
    v[6] = (short)f2bf(b.z); v[7] = (short)f2bf(b.w);
    *(bf16x8*)((char*)Wl + row * 256 + ((cb ^ (row & 7)) << 4)) = v;
  }
  __syncthreads();

  int l = t & 63;
  int w = t >> 6;
  int kg = l >> 4;
  int m_base = blockIdx.x * 64 + w * 16;
  int arow = m_base + (l & 15);
  if (arow >= N) arow = N - 1;

  bf16x8 af[4];
  const float* ap = io + (size_t)arow * 128 + kg * 8;
#pragma unroll
  for (int kk = 0; kk < 4; ++kk) {
    float4 a = *(const float4*)(ap + kk * 32);
    float4 b = *(const float4*)(ap + kk * 32 + 4);
    bf16x8 v;
    v[0] = (short)f2bf(a.x); v[1] = (short)f2bf(a.y);
    v[2] = (short)f2bf(a.z); v[3] = (short)f2bf(a.w);
    v[4] = (short)f2bf(b.x); v[5] = (short)f2bf(b.y);
    v[6] = (short)f2bf(b.z); v[7] = (short)f2bf(b.w);
    af[kk] = v;
  }

#pragma unroll
  for (int c = 0; c < 8; ++c) {
    f32x4 acc = {0.f, 0.f, 0.f, 0.f};
    int row_w = c * 16 + (l & 15);
    int rs = row_w & 7;
#pragma unroll
    for (int kk = 0; kk < 4; ++kk) {
      int cb = kk * 4 + kg;
      bf16x8 bf = *(bf16x8*)((char*)Wl + row_w * 256 + ((cb ^ rs) << 4));
      acc = __builtin_amdgcn_mfma_f32_16x16x32_bf16(af[kk], bf, acc, 0, 0, 0);
    }
    int j = c * 16 + (l & 15);
    float bj = bias[j];
#pragma unroll
    for (int r = 0; r < 4; ++r) {
      int m = m_base + kg * 4 + r;
      if (m < N) io[(size_t)m * 128 + j] = fmaxf(acc[r] + bj, 0.0f);
    }
  }
}

extern "C" void kernel_launch(void* const* d_in, const int* in_sizes, int n_in,
                              void* d_out, int out_size, void* d_ws, size_t ws_size,
                              hipStream_t stream) {
  const float* h     = (const float*)d_in[0];
  const float* alpha = (const float*)d_in[1];
  const float* ew    = (const float*)d_in[2];
  const float* W     = (const float*)d_in[3];
  const float* bias  = (const float*)d_in[4];
  const int* node_id = (const int*)d_in[5];
  const int* esrc    = (const int*)d_in[6];
  const int* edst    = (const int*)d_in[7];
  float* out = (float*)d_out;

  int E = in_sizes[2];
  int N = in_sizes[5];
  int gene_num = in_sizes[1] - 2;
  int npart = (N + PSIZE - 1) / PSIZE;          // 782 (must be <= 1024)
  int eblocks = (E + EDGES_PER_BLK - 1) / EDGES_PER_BLK;  // 245
  int total4 = N * D / 4;
  int cvtBlocks = (total4 + 511) / 512;         // 3125

  // workspace layout
  int* g_hist   = (int*)d_ws;                   // 1024
  int* part_off = g_hist + MAXPART;             // npart+1 (<=1025)
  int* g_cursor = part_off + MAXPART + 1;       // 1024
  int* cnt_g    = g_cursor + MAXPART;           // npart*64 <= 65536
  int* off_g    = cnt_g + MAXPART * PSIZE;      // npart*64 <= 65536
  int* pad_g    = off_g + MAXPART * PSIZE;      // npart*64 <= 65536
  size_t h16_off = ((size_t)(3 * MAXPART + 1 + 3 * MAXPART * PSIZE) * sizeof(int)
                    + 15) & ~(size_t)15;
  unsigned short* h16 = (unsigned short*)((char*)d_ws + h16_off);  // chunk-major
  size_t rec_off = (h16_off + (size_t)N * D * sizeof(unsigned short) + 15) & ~(size_t)15;
  int2* recs = (int2*)((char*)d_ws + rec_off);  // E * 8B
  size_t need = rec_off + (size_t)E * sizeof(int2);
  if (ws_size < need) return;

  hipMemsetAsync(g_hist, 0, MAXPART * sizeof(int), stream);

  cvt_hist_kernel<<<cvtBlocks + eblocks, 512, 0, stream>>>(
      h, h16, total4, edst, g_hist, E, cvtBlocks, N);
  part_scan_kernel<<<1, 512, 0, stream>>>(g_hist, part_off, g_cursor, E, npart);
  bin_scatter_kernel<<<eblocks, 512, 0, stream>>>(alpha, ew, node_id, esrc,
                                                  edst, g_cursor, recs, E,
                                                  gene_num);
  sort_kernel<<<npart, 512, 0, stream>>>(recs, part_off, cnt_g, off_g, pad_g);
  part_acc_kernel<<<npart * NCHUNK, 512, 0, stream>>>(h16, recs, part_off,
                                                      cnt_g, off_g, pad_g,
                                                      out, N);
  {
    int blocks = (N + 63) / 64;
    mlp_mfma_kernel<<<blocks, 256, 0, stream>>>(W, bias, out, N);
  }
}